// Round 7
// baseline (277.916 us; speedup 1.0000x reference)
//
#include <hip/hip_runtime.h>

typedef __attribute__((ext_vector_type(8))) _Float16 f16x8;
typedef __attribute__((ext_vector_type(2))) __fp16 fp16v2;
typedef __attribute__((ext_vector_type(4))) float f32x4;
typedef _Float16 f16;
typedef unsigned short u16;
typedef unsigned int u32;

#define DEV __device__ __forceinline__

DEV u32 packh2(float a, float b) {
  union { f16 h[2]; u32 u; } x;
  x.h[0] = (f16)a; x.h[1] = (f16)b;
  return x.u;
}
DEV u32 pkrtz(float a, float b) {
  union { fp16v2 h; u32 u; } x;
  x.h = __builtin_amdgcn_cvt_pkrtz(a, b);
  return x.u;
}
DEV float exp2_fast(float x) {
  float r;
  asm("v_exp_f32 %0, %1" : "=v"(r) : "v"(x));
  return r;
}

typedef __attribute__((address_space(1))) const u32 ASG_u32;
typedef __attribute__((address_space(3))) u32 ASL_u32;
DEV void gload16(const void* g, void* l) {
  __builtin_amdgcn_global_load_lds((ASG_u32*)g, (ASL_u32*)l, 16, 0, 0);
}

// ---------------- kernel 1: x (fp32 -> fp16) ----------------
__global__ __launch_bounds__(256) void k_half_x(const float* __restrict__ x,
                                                f16* __restrict__ xh) {
  const size_t i = ((size_t)blockIdx.x * 256 + threadIdx.x) * 8;
  float4 a = *(const float4*)(x + i);
  float4 c = *(const float4*)(x + i + 4);
  uint4 u;
  u.x = packh2(a.x, a.y); u.y = packh2(a.z, a.w);
  u.z = packh2(c.x, c.y); u.w = packh2(c.z, c.w);
  *(uint4*)(xh + i) = u;
}

// ------------- kernel 2: transpose W -> Wt[w][h][d][1024] fp16 -------------
__global__ __launch_bounds__(256) void k_prep_w(const float* __restrict__ Wq,
                                                const float* __restrict__ Wk,
                                                const float* __restrict__ Wv,
                                                f16* __restrict__ wt) {
  __shared__ float tile[64][65];
  const int bx = blockIdx.x;        // 0..767
  const int w = bx >> 8;
  const int rem = bx & 255;
  const int h = rem >> 4;
  const int nc = rem & 15;          // 64-wide chunk of d_model
  const float* W = (w == 0) ? Wq : ((w == 1) ? Wk : Wv);
  const int t = threadIdx.x;

  {
    const int r = t >> 2;
    const int cc = (t & 3) * 16;
    const float* src = W + ((size_t)h * 1024 + nc * 64 + r) * 64 + cc;
#pragma unroll
    for (int j = 0; j < 4; ++j) {
      float4 v = *(const float4*)(src + j * 4);
      tile[r][cc + j * 4 + 0] = v.x;
      tile[r][cc + j * 4 + 1] = v.y;
      tile[r][cc + j * 4 + 2] = v.z;
      tile[r][cc + j * 4 + 3] = v.w;
    }
  }
  __syncthreads();
  {
    const int d = t >> 2;
    const int n0 = (t & 3) * 16;
    const size_t base = ((size_t)(w * 16 + h) * 64 + d) * 1024 + nc * 64 + n0;
    uint4 u0, u1;
    u0.x = packh2(tile[n0 + 0][d], tile[n0 + 1][d]);
    u0.y = packh2(tile[n0 + 2][d], tile[n0 + 3][d]);
    u0.z = packh2(tile[n0 + 4][d], tile[n0 + 5][d]);
    u0.w = packh2(tile[n0 + 6][d], tile[n0 + 7][d]);
    u1.x = packh2(tile[n0 + 8][d], tile[n0 + 9][d]);
    u1.y = packh2(tile[n0 + 10][d], tile[n0 + 11][d]);
    u1.z = packh2(tile[n0 + 12][d], tile[n0 + 13][d]);
    u1.w = packh2(tile[n0 + 14][d], tile[n0 + 15][d]);
    *(uint4*)(wt + base) = u0;
    *(uint4*)(wt + base + 8) = u1;
  }
}

// ------------- kernel 3: projection GEMM (fp16) -------------
__global__ __launch_bounds__(256, 4) void k_proj(
    const f16* __restrict__ xh, const f16* __restrict__ wt,
    f16* __restrict__ Q, f16* __restrict__ K, f16* __restrict__ Vt) {
  __shared__ __align__(16) char ldsb[24576];  // A 16K | B 8K
  int bid = blockIdx.x;
  bid = (bid & 7) * 384 + (bid >> 3);  // XCD swizzle (3072 % 8 == 0, bijective)
  const int bm = bid / 48;
  const int bn = bid % 48;
  const int w = bn >> 4;
  const int h = bn & 15;
  const bool isV = (w == 2);
  const int t = threadIdx.x;
  const int wave = t >> 6;
  const int lane = t & 63;
  const int wr = wave >> 1;
  const int wc = wave & 1;

  f32x4 acc[4][2];
#pragma unroll
  for (int mi = 0; mi < 4; ++mi)
#pragma unroll
    for (int ni = 0; ni < 2; ++ni) acc[mi][ni] = (f32x4)(0.0f);

  for (int kt = 0; kt < 16; ++kt) {
    const int k0 = kt * 64;
#pragma unroll
    for (int i = 0; i < 4; ++i) {
      const int ci = wave * 4 + i;                 // 0..15
      const int row = ci * 8 + (lane >> 3);        // 0..127
      const int cb = ((lane & 7) * 16) ^ ((row & 7) << 4);
      const size_t gb = ((size_t)(bm * 128 + row) * 1024 + k0) * 2;
      gload16((const char*)xh + gb + cb, ldsb + ci * 1024);
    }
#pragma unroll
    for (int i = 0; i < 2; ++i) {
      const int ci = wave * 2 + i;                 // 0..7
      const int row = ci * 8 + (lane >> 3);        // 0..63
      const int cb = ((lane & 7) * 16) ^ ((row & 7) << 4);
      const size_t gb = ((size_t)(bn * 64 + row) * 1024 + k0) * 2;
      gload16((const char*)wt + gb + cb, ldsb + 16384 + ci * 1024);
    }
    __syncthreads();

#pragma unroll
    for (int ks = 0; ks < 2; ++ks) {
      f16x8 af[4], bfr[2];
#pragma unroll
      for (int mi = 0; mi < 4; ++mi) {
        const int row = wr * 64 + mi * 16 + (lane & 15);
        const int cb = (((lane >> 4) * 16) + ks * 64) ^ ((row & 7) << 4);
        af[mi] = *(const f16x8*)(ldsb + row * 128 + cb);
      }
#pragma unroll
      for (int ni = 0; ni < 2; ++ni) {
        const int row = wc * 32 + ni * 16 + (lane & 15);
        const int cb = (((lane >> 4) * 16) + ks * 64) ^ ((row & 7) << 4);
        bfr[ni] = *(const f16x8*)(ldsb + 16384 + row * 128 + cb);
      }
#pragma unroll
      for (int mi = 0; mi < 4; ++mi)
#pragma unroll
        for (int ni = 0; ni < 2; ++ni)
          acc[mi][ni] = __builtin_amdgcn_mfma_f32_16x16x32_f16(af[mi], bfr[ni], acc[mi][ni], 0, 0, 0);
    }
    __syncthreads();
  }

  // epilogue
  const int rb = bm * 128 + wr * 64;
#pragma unroll
  for (int mi = 0; mi < 4; ++mi) {
#pragma unroll
    for (int ni = 0; ni < 2; ++ni) {
      f32x4 v = acc[mi][ni];
      const int d = wc * 32 + ni * 16 + (lane & 15);
      const int m0 = rb + mi * 16 + ((lane >> 4) << 2);
      const int b = m0 >> 11;
      const int ml = m0 & 2047;
      if (isV) {
        uint2 u;
        u.x = packh2(v[0], v[1]);
        u.y = packh2(v[2], v[3]);
        *(uint2*)(Vt + ((size_t)((b * 16 + h) * 64 + d)) * 2048 + ml) = u;
      } else {
        // Q: fold 1/sqrt(64) AND log2(e) (softmax done in exp2 domain)
        const float sc = (w == 0) ? 0.18033688f : 1.0f;
        f16* A = (w == 0) ? Q : K;
#pragma unroll
        for (int j = 0; j < 4; ++j)
          A[((size_t)(b * 16 + h) * 2048 + (ml + j)) * 64 + d] = (f16)(v[j] * sc);
      }
    }
  }
}

// ------- kernel 4: flash attention (swapped QK^T, K-only LDS, V from L2) -------
__global__ __launch_bounds__(256, 4) void k_attn(
    const f16* __restrict__ Q, const f16* __restrict__ K,
    const f16* __restrict__ Vt, float* __restrict__ out) {
  // LDS: 2 x K 8K dbuf = 16K | P 4 x 4096B  => 32768 total, 4 blocks/CU
  __shared__ __align__(16) char ldsb[32768];
  int bid = blockIdx.x;
  bid = (bid & 7) * 128 + (bid >> 3);  // XCD swizzle (1024 % 8 == 0, bijective)
  const int bh = bid >> 4;
  const int qt = bid & 15;
  const int b = bh >> 4;
  const int h = bh & 15;
  const int t = threadIdx.x;
  const int wave = t >> 6;
  const int lane = t & 63;
  const int l15 = lane & 15;
  const int g = lane >> 4;
  char* sP = ldsb + 16384 + wave * 4096;  // per-wave P[32 rows][128 B], XOR-swizzled

  f16x8 qf[2][2];
  const size_t qbase = ((size_t)bh * 2048 + qt * 128 + wave * 32) * 64;
#pragma unroll
  for (int mf = 0; mf < 2; ++mf)
#pragma unroll
    for (int ks = 0; ks < 2; ++ks) {
      const size_t off = qbase + (size_t)(mf * 16 + l15) * 64 + ks * 32 + g * 8;
      qf[mf][ks] = *(const f16x8*)(Q + off);
    }

  f32x4 o[2][4];
  float ms[2], ls[2];
#pragma unroll
  for (int mf = 0; mf < 2; ++mf) { ms[mf] = -1e30f; ls[mf] = 0.0f; }
#pragma unroll
  for (int mf = 0; mf < 2; ++mf)
#pragma unroll
    for (int df = 0; df < 4; ++df) o[mf][df] = (f32x4)(0.0f);

  const size_t kvbase = (size_t)bh * 2048 * 64;

  // per-thread staging addresses (hoisted)
  const int srow = (wave * 2) * 8 + (lane >> 3);           // rows for i=0; i=1 adds 8
  const int scb0 = ((lane & 7) * 16) ^ ((srow & 7) << 4);  // row&7 same for row, row+8

#pragma unroll 1
  for (int kt = 0; kt < 33; ++kt) {
    // stage K tile kt into buf kt&1 (issued one iteration ahead of use)
    if (kt < 32) {
      char* dst = ldsb + (kt & 1) * 8192;
#pragma unroll
      for (int i = 0; i < 2; ++i) {
        const int ci = wave * 2 + i;
        const int row = srow + i * 8;
        const size_t gk = (kvbase + (size_t)(kt * 64 + row) * 64) * 2;
        gload16((const char*)K + gk + scb0, dst + ci * 1024);
      }
    }
    if (kt == 0) { __syncthreads(); continue; }
    const int m0kv = (kt - 1) * 64;  // kv base of compute tile
    const char* kb = ldsb + ((kt - 1) & 1) * 8192;

    // S^T = mfma(K_frag, Q_frag): lane holds, per mf, 16 k-values of q = mf*16+l15
    f32x4 st[2][4];
#pragma unroll
    for (int mf = 0; mf < 2; ++mf)
#pragma unroll
      for (int nf = 0; nf < 4; ++nf) st[mf][nf] = (f32x4)(0.0f);
#pragma unroll
    for (int ks = 0; ks < 2; ++ks) {
      f16x8 kf[4];
#pragma unroll
      for (int nf = 0; nf < 4; ++nf) {
        const int row = nf * 16 + l15;
        const int cb = ((g * 16) + ks * 64) ^ ((row & 7) << 4);
        kf[nf] = *(const f16x8*)(kb + row * 128 + cb);
      }
#pragma unroll
      for (int mf = 0; mf < 2; ++mf)
#pragma unroll
        for (int nf = 0; nf < 4; ++nf)
          st[mf][nf] = __builtin_amdgcn_mfma_f32_16x16x32_f16(kf[nf], qf[mf][ks], st[mf][nf], 0, 0, 0);
    }

    // V fragments straight from global (L2-resident; per-lane 16B contiguous).
    // Issued before softmax so ~200cy L2 latency hides under the VALU phase.
    f16x8 vr[2][4];
#pragma unroll
    for (int ks = 0; ks < 2; ++ks)
#pragma unroll
      for (int df = 0; df < 4; ++df)
        vr[ks][df] = *(const f16x8*)(Vt + kvbase + (size_t)(df * 16 + l15) * 2048 +
                                     m0kv + ks * 32 + g * 8);

    // lane-local online softmax (logits in log2 domain; Q pre-scaled)
#pragma unroll
    for (int mf = 0; mf < 2; ++mf) {
      float rm = fmaxf(fmaxf(fmaxf(st[mf][0][0], st[mf][0][1]), fmaxf(st[mf][0][2], st[mf][0][3])),
                       fmaxf(fmaxf(st[mf][1][0], st[mf][1][1]), fmaxf(st[mf][1][2], st[mf][1][3])));
      rm = fmaxf(rm, fmaxf(fmaxf(fmaxf(st[mf][2][0], st[mf][2][1]), fmaxf(st[mf][2][2], st[mf][2][3])),
                           fmaxf(fmaxf(st[mf][3][0], st[mf][3][1]), fmaxf(st[mf][3][2], st[mf][3][3]))));
      rm = fmaxf(rm, __shfl_xor(rm, 16));
      rm = fmaxf(rm, __shfl_xor(rm, 32));
      if (__any(rm > ms[mf] + 11.5f)) {   // defer-max (THR=8 in base-e)
        const float mnew = fmaxf(ms[mf], rm);
        const float alpha = exp2_fast(ms[mf] - mnew);
        ms[mf] = mnew;
        ls[mf] *= alpha;
        f32x4 av;
#pragma unroll
        for (int j = 0; j < 4; ++j) av[j] = __shfl(alpha, g * 4 + j);
#pragma unroll
        for (int df = 0; df < 4; ++df) o[mf][df] *= av;
      }
      const float m = ms[mf];
      float p[4][4], part = 0.0f;
#pragma unroll
      for (int nf = 0; nf < 4; ++nf) {
#pragma unroll
        for (int j = 0; j < 4; ++j) {
          p[nf][j] = exp2_fast(st[mf][nf][j] - m);
          part += p[nf][j];
        }
      }
      ls[mf] += part;
      const int prow = mf * 16 + l15;
      char* pr = sP + prow * 128;
      const int swz = (prow & 7) << 4;
#pragma unroll
      for (int nf = 0; nf < 4; ++nf) {
        uint2 u;
        u.x = pkrtz(p[nf][0], p[nf][1]);
        u.y = pkrtz(p[nf][2], p[nf][3]);
        *(uint2*)(pr + (((nf << 5) + (g << 3)) ^ swz)) = u;
      }
    }
    asm volatile("" ::: "memory");  // order P ds_writes before pa ds_reads

#pragma unroll
    for (int ks = 0; ks < 2; ++ks) {
      f16x8 pa[2];
#pragma unroll
      for (int mf = 0; mf < 2; ++mf) {
        const int prow = mf * 16 + l15;
        pa[mf] = *(const f16x8*)(sP + prow * 128 + ((ks * 64 + g * 16) ^ ((prow & 7) << 4)));
      }
#pragma unroll
      for (int df = 0; df < 4; ++df) {
#pragma unroll
        for (int mf = 0; mf < 2; ++mf)
          o[mf][df] = __builtin_amdgcn_mfma_f32_16x16x32_f16(pa[mf], vr[ks][df], o[mf][df], 0, 0, 0);
      }
    }
    __syncthreads();  // publishes K buf staged this iteration; guards P reuse
  }

  // epilogue: O fragment rows are q = mf*16 + g*4 + j; l lives at lane l15 == q
#pragma unroll
  for (int mf = 0; mf < 2; ++mf) {
    float l = ls[mf];
    l += __shfl_xor(l, 16);
    l += __shfl_xor(l, 32);
    const float inv = 1.0f / l;
    f32x4 iv;
#pragma unroll
    for (int j = 0; j < 4; ++j) iv[j] = __shfl(inv, g * 4 + j);
#pragma unroll
    for (int j = 0; j < 4; ++j) {
      const int m = qt * 128 + wave * 32 + mf * 16 + g * 4 + j;
#pragma unroll
      for (int df = 0; df < 4; ++df) {
        const int d = df * 16 + l15;
        out[((size_t)(b * 2048 + m)) * 1024 + h * 64 + d] = o[mf][df][j] * iv[j];
      }
    }
  }
}

// ---------------- launch ----------------
extern "C" void kernel_launch(void* const* d_in, const int* in_sizes, int n_in,
                              void* d_out, int out_size, void* d_ws, size_t ws_size,
                              hipStream_t stream) {
  (void)in_sizes; (void)n_in; (void)out_size; (void)ws_size;
  const float* x  = (const float*)d_in[0];
  const float* Wq = (const float*)d_in[1];
  const float* Wk = (const float*)d_in[2];
  const float* Wv = (const float*)d_in[3];
  float* out = (float*)d_out;

  f16* ws = (f16*)d_ws;  // element (f16) offsets
  f16* xh = ws + 0;            // 8192*1024
  f16* wt = ws + 8388608;      // 3*16*64*1024
  f16* Q  = ws + 11534336;     // 64*2048*64 each
  f16* K  = ws + 19922944;
  f16* Vt = ws + 28311552;     // [bh][64][2048]

  k_half_x<<<4096, 256, 0, stream>>>(x, xh);
  k_prep_w<<<768, 256, 0, stream>>>(Wq, Wk, Wv, wt);
  k_proj<<<3072, 256, 0, stream>>>(xh, wt, Q, K, Vt);
  k_attn<<<1024, 256, 0, stream>>>(Q, K, Vt, out);
}

// Round 10
// 191.649 us; speedup vs baseline: 1.4501x; 1.4501x over previous
//
#include <hip/hip_runtime.h>

typedef __attribute__((ext_vector_type(8))) _Float16 f16x8;
typedef __attribute__((ext_vector_type(2))) __fp16 fp16v2;
typedef __attribute__((ext_vector_type(4))) float f32x4;
typedef _Float16 f16;
typedef unsigned short u16;
typedef unsigned int u32;

#define DEV __device__ __forceinline__

DEV u32 packh2(float a, float b) {
  union { f16 h[2]; u32 u; } x;
  x.h[0] = (f16)a; x.h[1] = (f16)b;
  return x.u;
}
DEV u32 pkrtz(float a, float b) {
  union { fp16v2 h; u32 u; } x;
  x.h = __builtin_amdgcn_cvt_pkrtz(a, b);
  return x.u;
}
DEV float exp2_fast(float x) {
  float r;
  asm("v_exp_f32 %0, %1" : "=v"(r) : "v"(x));
  return r;
}

typedef __attribute__((address_space(1))) const u32 ASG_u32;
typedef __attribute__((address_space(3))) u32 ASL_u32;
DEV void gload16(const void* g, void* l) {
  __builtin_amdgcn_global_load_lds((ASG_u32*)g, (ASL_u32*)l, 16, 0, 0);
}

// ---------------- kernel 1: x (fp32 -> fp16) ----------------
__global__ __launch_bounds__(256) void k_half_x(const float* __restrict__ x,
                                                f16* __restrict__ xh) {
  const size_t i = ((size_t)blockIdx.x * 256 + threadIdx.x) * 8;
  float4 a = *(const float4*)(x + i);
  float4 c = *(const float4*)(x + i + 4);
  uint4 u;
  u.x = packh2(a.x, a.y); u.y = packh2(a.z, a.w);
  u.z = packh2(c.x, c.y); u.w = packh2(c.z, c.w);
  *(uint4*)(xh + i) = u;
}

// ------------- kernel 2: transpose W -> Wt[w][h][d][1024] fp16 -------------
__global__ __launch_bounds__(256) void k_prep_w(const float* __restrict__ Wq,
                                                const float* __restrict__ Wk,
                                                const float* __restrict__ Wv,
                                                f16* __restrict__ wt) {
  __shared__ float tile[64][65];
  const int bx = blockIdx.x;        // 0..767
  const int w = bx >> 8;
  const int rem = bx & 255;
  const int h = rem >> 4;
  const int nc = rem & 15;          // 64-wide chunk of d_model
  const float* W = (w == 0) ? Wq : ((w == 1) ? Wk : Wv);
  const int t = threadIdx.x;

  {
    const int r = t >> 2;
    const int cc = (t & 3) * 16;
    const float* src = W + ((size_t)h * 1024 + nc * 64 + r) * 64 + cc;
#pragma unroll
    for (int j = 0; j < 4; ++j) {
      float4 v = *(const float4*)(src + j * 4);
      tile[r][cc + j * 4 + 0] = v.x;
      tile[r][cc + j * 4 + 1] = v.y;
      tile[r][cc + j * 4 + 2] = v.z;
      tile[r][cc + j * 4 + 3] = v.w;
    }
  }
  __syncthreads();
  {
    const int d = t >> 2;
    const int n0 = (t & 3) * 16;
    const size_t base = ((size_t)(w * 16 + h) * 64 + d) * 1024 + nc * 64 + n0;
    uint4 u0, u1;
    u0.x = packh2(tile[n0 + 0][d], tile[n0 + 1][d]);
    u0.y = packh2(tile[n0 + 2][d], tile[n0 + 3][d]);
    u0.z = packh2(tile[n0 + 4][d], tile[n0 + 5][d]);
    u0.w = packh2(tile[n0 + 6][d], tile[n0 + 7][d]);
    u1.x = packh2(tile[n0 + 8][d], tile[n0 + 9][d]);
    u1.y = packh2(tile[n0 + 10][d], tile[n0 + 11][d]);
    u1.z = packh2(tile[n0 + 12][d], tile[n0 + 13][d]);
    u1.w = packh2(tile[n0 + 14][d], tile[n0 + 15][d]);
    *(uint4*)(wt + base) = u0;
    *(uint4*)(wt + base + 8) = u1;
  }
}

// ------------- kernel 3: projection GEMM (fp16), 128x128 tiles -------------
// C[8192 x 3072] = xh[8192 x 1024] @ wt^T; column tile = 2 heads of one w-type.
__global__ __launch_bounds__(256, 4) void k_proj(
    const f16* __restrict__ xh, const f16* __restrict__ wt,
    f16* __restrict__ Q, f16* __restrict__ K, f16* __restrict__ Vt) {
  __shared__ __align__(16) char ldsb[32768];  // A 16K | B 16K
  int bid = blockIdx.x;
  bid = (bid & 7) * 192 + (bid >> 3);  // XCD swizzle (1536 % 8 == 0, bijective)
  const int bm = bid / 24;             // 0..63 (128-row tile)
  const int bn = bid % 24;             // w = bn/8, head-pair = bn%8
  const int w = bn >> 3;
  const int hp = bn & 7;
  const int wrow = w * 1024 + hp * 128;  // first wt row of this column tile
  const bool isV = (w == 2);
  const int t = threadIdx.x;
  const int wave = t >> 6;
  const int lane = t & 63;
  const int l15 = lane & 15;
  const int wr = wave >> 1;
  const int wc = wave & 1;

  f32x4 acc[4][4];
#pragma unroll
  for (int mi = 0; mi < 4; ++mi)
#pragma unroll
    for (int ni = 0; ni < 4; ++ni) acc[mi][ni] = (f32x4)(0.0f);

  for (int kt = 0; kt < 16; ++kt) {
    const int k0 = kt * 64;
#pragma unroll
    for (int i = 0; i < 4; ++i) {
      const int ci = wave * 4 + i;                 // 0..15
      const int row = ci * 8 + (lane >> 3);        // 0..127
      const int cb = ((lane & 7) * 16) ^ ((row & 7) << 4);
      const size_t ga = ((size_t)(bm * 128 + row) * 1024 + k0) * 2;
      gload16((const char*)xh + ga + cb, ldsb + ci * 1024);
      const size_t gb = ((size_t)(wrow + row) * 1024 + k0) * 2;
      gload16((const char*)wt + gb + cb, ldsb + 16384 + ci * 1024);
    }
    __syncthreads();

#pragma unroll
    for (int ks = 0; ks < 2; ++ks) {
      f16x8 af[4], bfr[4];
#pragma unroll
      for (int mi = 0; mi < 4; ++mi) {
        const int row = wr * 64 + mi * 16 + l15;
        const int cb = (((lane >> 4) * 16) + ks * 64) ^ ((row & 7) << 4);
        af[mi] = *(const f16x8*)(ldsb + row * 128 + cb);
      }
#pragma unroll
      for (int ni = 0; ni < 4; ++ni) {
        const int row = wc * 64 + ni * 16 + l15;
        const int cb = (((lane >> 4) * 16) + ks * 64) ^ ((row & 7) << 4);
        bfr[ni] = *(const f16x8*)(ldsb + 16384 + row * 128 + cb);
      }
#pragma unroll
      for (int mi = 0; mi < 4; ++mi)
#pragma unroll
        for (int ni = 0; ni < 4; ++ni)
          acc[mi][ni] = __builtin_amdgcn_mfma_f32_16x16x32_f16(af[mi], bfr[ni], acc[mi][ni], 0, 0, 0);
    }
    __syncthreads();
  }

  // epilogue: columns 0..127 = head hp*2 + (dl>>6), d = dl & 63
  const int rb = bm * 128 + wr * 64;
#pragma unroll
  for (int mi = 0; mi < 4; ++mi) {
#pragma unroll
    for (int ni = 0; ni < 4; ++ni) {
      f32x4 v = acc[mi][ni];
      const int dl = wc * 64 + ni * 16 + l15;
      const int hh = hp * 2 + (dl >> 6);
      const int d = dl & 63;
      const int m0 = rb + mi * 16 + ((lane >> 4) << 2);
      const int b = m0 >> 11;
      const int ml = m0 & 2047;
      if (isV) {
        uint2 u;
        u.x = packh2(v[0], v[1]);
        u.y = packh2(v[2], v[3]);
        *(uint2*)(Vt + ((size_t)((b * 16 + hh) * 64 + d)) * 2048 + ml) = u;
      } else {
        // Q: fold 1/sqrt(64) AND log2(e) (softmax done in exp2 domain)
        const float sc = (w == 0) ? 0.18033688f : 1.0f;
        f16* A = (w == 0) ? Q : K;
#pragma unroll
        for (int j = 0; j < 4; ++j)
          A[((size_t)(b * 16 + hh) * 2048 + (ml + j)) * 64 + d] = (f16)(v[j] * sc);
      }
    }
  }
}

// ------- kernel 4: flash attention (R5-exact: swapped QK^T, defer-max) -------
__global__ __launch_bounds__(256, 3) void k_attn(
    const f16* __restrict__ Q, const f16* __restrict__ K,
    const f16* __restrict__ Vt, float* __restrict__ out) {
  // LDS: 2 x (K 8K | Vt 8K) dbuf = 32K | P 4 x 4096B
  __shared__ __align__(16) char ldsb[49152];
  int bid = blockIdx.x;
  bid = (bid & 7) * 128 + (bid >> 3);  // XCD swizzle (1024 % 8 == 0, bijective)
  const int bh = bid >> 4;
  const int qt = bid & 15;
  const int b = bh >> 4;
  const int h = bh & 15;
  const int t = threadIdx.x;
  const int wave = t >> 6;
  const int lane = t & 63;
  const int l15 = lane & 15;
  const int g = lane >> 4;
  char* sP = ldsb + 32768 + wave * 4096;  // per-wave P[32 rows][128 B], XOR-swizzled

  f16x8 qf[2][2];
  const size_t qbase = ((size_t)bh * 2048 + qt * 128 + wave * 32) * 64;
#pragma unroll
  for (int mf = 0; mf < 2; ++mf)
#pragma unroll
    for (int ks = 0; ks < 2; ++ks) {
      const size_t off = qbase + (size_t)(mf * 16 + l15) * 64 + ks * 32 + g * 8;
      qf[mf][ks] = *(const f16x8*)(Q + off);
    }

  f32x4 o[2][4];
  float ms[2], ls[2];
#pragma unroll
  for (int mf = 0; mf < 2; ++mf) { ms[mf] = -1e30f; ls[mf] = 0.0f; }
#pragma unroll
  for (int mf = 0; mf < 2; ++mf)
#pragma unroll
    for (int df = 0; df < 4; ++df) o[mf][df] = (f32x4)(0.0f);

  const size_t kvbase = (size_t)bh * 2048 * 64;

  // per-thread staging addresses (hoisted)
  const int srow = (wave * 2) * 8 + (lane >> 3);           // rows for i=0; i=1 adds 8
  const int scb0 = ((lane & 7) * 16) ^ ((srow & 7) << 4);  // row&7 same for row, row+8

#pragma unroll 1
  for (int kt = 0; kt < 33; ++kt) {
    // stage tile kt into buf kt&1 (issued one iteration ahead of use)
    if (kt < 32) {
      char* dst = ldsb + (kt & 1) * 16384;
#pragma unroll
      for (int i = 0; i < 2; ++i) {
        const int ci = wave * 2 + i;
        const int row = srow + i * 8;
        const size_t gk = (kvbase + (size_t)(kt * 64 + row) * 64) * 2;
        gload16((const char*)K + gk + scb0, dst + ci * 1024);
        const size_t gv = (kvbase + (size_t)row * 2048 + kt * 64) * 2;
        gload16((const char*)Vt + gv + scb0, dst + 8192 + ci * 1024);
      }
    }
    if (kt == 0) { __syncthreads(); continue; }
    const char* kb = ldsb + ((kt - 1) & 1) * 16384;
    const char* vbuf = kb + 8192;

    // S^T = mfma(K_frag, Q_frag): lane holds, per mf, 16 k-values of q = mf*16+l15
    f32x4 st[2][4];
#pragma unroll
    for (int mf = 0; mf < 2; ++mf)
#pragma unroll
      for (int nf = 0; nf < 4; ++nf) st[mf][nf] = (f32x4)(0.0f);
#pragma unroll
    for (int ks = 0; ks < 2; ++ks) {
      f16x8 kf[4];
#pragma unroll
      for (int nf = 0; nf < 4; ++nf) {
        const int row = nf * 16 + l15;
        const int cb = ((g * 16) + ks * 64) ^ ((row & 7) << 4);
        kf[nf] = *(const f16x8*)(kb + row * 128 + cb);
      }
#pragma unroll
      for (int mf = 0; mf < 2; ++mf)
#pragma unroll
        for (int nf = 0; nf < 4; ++nf)
          st[mf][nf] = __builtin_amdgcn_mfma_f32_16x16x32_f16(kf[nf], qf[mf][ks], st[mf][nf], 0, 0, 0);
    }

    // lane-local online softmax (logits in log2 domain; Q pre-scaled)
#pragma unroll
    for (int mf = 0; mf < 2; ++mf) {
      float rm = fmaxf(fmaxf(fmaxf(st[mf][0][0], st[mf][0][1]), fmaxf(st[mf][0][2], st[mf][0][3])),
                       fmaxf(fmaxf(st[mf][1][0], st[mf][1][1]), fmaxf(st[mf][1][2], st[mf][1][3])));
      rm = fmaxf(rm, fmaxf(fmaxf(fmaxf(st[mf][2][0], st[mf][2][1]), fmaxf(st[mf][2][2], st[mf][2][3])),
                           fmaxf(fmaxf(st[mf][3][0], st[mf][3][1]), fmaxf(st[mf][3][2], st[mf][3][3]))));
      rm = fmaxf(rm, __shfl_xor(rm, 16));
      rm = fmaxf(rm, __shfl_xor(rm, 32));
      if (__any(rm > ms[mf] + 11.5f)) {   // defer-max (THR=8 in base-e)
        const float mnew = fmaxf(ms[mf], rm);
        const float alpha = exp2_fast(ms[mf] - mnew);
        ms[mf] = mnew;
        ls[mf] *= alpha;
        f32x4 av;
#pragma unroll
        for (int j = 0; j < 4; ++j) av[j] = __shfl(alpha, g * 4 + j);
#pragma unroll
        for (int df = 0; df < 4; ++df) o[mf][df] *= av;
      }
      const float m = ms[mf];
      float p[4][4], part = 0.0f;
#pragma unroll
      for (int nf = 0; nf < 4; ++nf) {
#pragma unroll
        for (int j = 0; j < 4; ++j) {
          p[nf][j] = exp2_fast(st[mf][nf][j] - m);
          part += p[nf][j];
        }
      }
      ls[mf] += part;
      const int prow = mf * 16 + l15;
      char* pr = sP + prow * 128;
      const int swz = (prow & 7) << 4;
#pragma unroll
      for (int nf = 0; nf < 4; ++nf) {
        uint2 u;
        u.x = pkrtz(p[nf][0], p[nf][1]);
        u.y = pkrtz(p[nf][2], p[nf][3]);
        *(uint2*)(pr + (((nf << 5) + (g << 3)) ^ swz)) = u;
      }
    }
    asm volatile("" ::: "memory");  // order P ds_writes before pa ds_reads

#pragma unroll
    for (int ks = 0; ks < 2; ++ks) {
      f16x8 pa[2];
#pragma unroll
      for (int mf = 0; mf < 2; ++mf) {
        const int prow = mf * 16 + l15;
        pa[mf] = *(const f16x8*)(sP + prow * 128 + ((ks * 64 + g * 16) ^ ((prow & 7) << 4)));
      }
#pragma unroll
      for (int df = 0; df < 4; ++df) {
        const int row = df * 16 + l15;
        const int cb = ((g * 16) + ks * 64) ^ ((row & 7) << 4);
        const f16x8 vb = *(const f16x8*)(vbuf + row * 128 + cb);
#pragma unroll
        for (int mf = 0; mf < 2; ++mf)
          o[mf][df] = __builtin_amdgcn_mfma_f32_16x16x32_f16(pa[mf], vb, o[mf][df], 0, 0, 0);
      }
    }
    __syncthreads();  // publishes buf staged this iteration; guards P reuse
  }

  // epilogue: O fragment rows are q = mf*16 + g*4 + j; l lives at lane l15 == q
#pragma unroll
  for (int mf = 0; mf < 2; ++mf) {
    float l = ls[mf];
    l += __shfl_xor(l, 16);
    l += __shfl_xor(l, 32);
    const float inv = 1.0f / l;
    f32x4 iv;
#pragma unroll
    for (int j = 0; j < 4; ++j) iv[j] = __shfl(inv, g * 4 + j);
#pragma unroll
    for (int j = 0; j < 4; ++j) {
      const int m = qt * 128 + wave * 32 + mf * 16 + g * 4 + j;
#pragma unroll
      for (int df = 0; df < 4; ++df) {
        const int d = df * 16 + l15;
        out[((size_t)(b * 2048 + m)) * 1024 + h * 64 + d] = o[mf][df][j] * iv[j];
      }
    }
  }
}

// ---------------- launch ----------------
extern "C" void kernel_launch(void* const* d_in, const int* in_sizes, int n_in,
                              void* d_out, int out_size, void* d_ws, size_t ws_size,
                              hipStream_t stream) {
  (void)in_sizes; (void)n_in; (void)out_size; (void)ws_size;
  const float* x  = (const float*)d_in[0];
  const float* Wq = (const float*)d_in[1];
  const float* Wk = (const float*)d_in[2];
  const float* Wv = (const float*)d_in[3];
  float* out = (float*)d_out;

  f16* ws = (f16*)d_ws;  // element (f16) offsets
  f16* xh = ws + 0;            // 8192*1024
  f16* wt = ws + 8388608;      // 3*16*64*1024
  f16* Q  = ws + 11534336;     // 64*2048*64 each
  f16* K  = ws + 19922944;
  f16* Vt = ws + 28311552;     // [bh][64][2048]

  k_half_x<<<4096, 256, 0, stream>>>(x, xh);
  k_prep_w<<<768, 256, 0, stream>>>(Wq, Wk, Wv, wt);
  k_proj<<<1536, 256, 0, stream>>>(xh, wt, Q, K, Vt);
  k_attn<<<1024, 256, 0, stream>>>(Q, K, Vt, out);
}

// Round 12
// 182.738 us; speedup vs baseline: 1.5208x; 1.0488x over previous
//
#include <hip/hip_runtime.h>

typedef __attribute__((ext_vector_type(8))) _Float16 f16x8;
typedef __attribute__((ext_vector_type(2))) __fp16 fp16v2;
typedef __attribute__((ext_vector_type(4))) float f32x4;
typedef _Float16 f16;
typedef unsigned short u16;
typedef unsigned int u32;

#define DEV __device__ __forceinline__

DEV u32 packh2(float a, float b) {
  union { f16 h[2]; u32 u; } x;
  x.h[0] = (f16)a; x.h[1] = (f16)b;
  return x.u;
}
DEV u32 pkrtz(float a, float b) {
  union { fp16v2 h; u32 u; } x;
  x.h = __builtin_amdgcn_cvt_pkrtz(a, b);
  return x.u;
}
DEV float exp2_fast(float x) {
  float r;
  asm("v_exp_f32 %0, %1" : "=v"(r) : "v"(x));
  return r;
}

typedef __attribute__((address_space(1))) const u32 ASG_u32;
typedef __attribute__((address_space(3))) u32 ASL_u32;
DEV void gload16(const void* g, void* l) {
  __builtin_amdgcn_global_load_lds((ASG_u32*)g, (ASL_u32*)l, 16, 0, 0);
}

// ---------------- kernel 1: x (fp32 -> fp16) ----------------
__global__ __launch_bounds__(256) void k_half_x(const float* __restrict__ x,
                                                f16* __restrict__ xh) {
  const size_t i = ((size_t)blockIdx.x * 256 + threadIdx.x) * 8;
  float4 a = *(const float4*)(x + i);
  float4 c = *(const float4*)(x + i + 4);
  uint4 u;
  u.x = packh2(a.x, a.y); u.y = packh2(a.z, a.w);
  u.z = packh2(c.x, c.y); u.w = packh2(c.z, c.w);
  *(uint4*)(xh + i) = u;
}

// ------------- kernel 2: transpose W -> Wt[w][h][d][1024] fp16 -------------
__global__ __launch_bounds__(256) void k_prep_w(const float* __restrict__ Wq,
                                                const float* __restrict__ Wk,
                                                const float* __restrict__ Wv,
                                                f16* __restrict__ wt) {
  __shared__ float tile[64][65];
  const int bx = blockIdx.x;        // 0..767
  const int w = bx >> 8;
  const int rem = bx & 255;
  const int h = rem >> 4;
  const int nc = rem & 15;          // 64-wide chunk of d_model
  const float* W = (w == 0) ? Wq : ((w == 1) ? Wk : Wv);
  const int t = threadIdx.x;

  {
    const int r = t >> 2;
    const int cc = (t & 3) * 16;
    const float* src = W + ((size_t)h * 1024 + nc * 64 + r) * 64 + cc;
#pragma unroll
    for (int j = 0; j < 4; ++j) {
      float4 v = *(const float4*)(src + j * 4);
      tile[r][cc + j * 4 + 0] = v.x;
      tile[r][cc + j * 4 + 1] = v.y;
      tile[r][cc + j * 4 + 2] = v.z;
      tile[r][cc + j * 4 + 3] = v.w;
    }
  }
  __syncthreads();
  {
    const int d = t >> 2;
    const int n0 = (t & 3) * 16;
    const size_t base = ((size_t)(w * 16 + h) * 64 + d) * 1024 + nc * 64 + n0;
    uint4 u0, u1;
    u0.x = packh2(tile[n0 + 0][d], tile[n0 + 1][d]);
    u0.y = packh2(tile[n0 + 2][d], tile[n0 + 3][d]);
    u0.z = packh2(tile[n0 + 4][d], tile[n0 + 5][d]);
    u0.w = packh2(tile[n0 + 6][d], tile[n0 + 7][d]);
    u1.x = packh2(tile[n0 + 8][d], tile[n0 + 9][d]);
    u1.y = packh2(tile[n0 + 10][d], tile[n0 + 11][d]);
    u1.z = packh2(tile[n0 + 12][d], tile[n0 + 13][d]);
    u1.w = packh2(tile[n0 + 14][d], tile[n0 + 15][d]);
    *(uint4*)(wt + base) = u0;
    *(uint4*)(wt + base + 8) = u1;
  }
}

// ------------- kernel 3: projection GEMM (fp16), 128x128 tiles -------------
// C[8192 x 3072] = xh[8192 x 1024] @ wt^T; column tile = 2 heads of one w-type.
__global__ __launch_bounds__(256, 4) void k_proj(
    const f16* __restrict__ xh, const f16* __restrict__ wt,
    f16* __restrict__ Q, f16* __restrict__ K, f16* __restrict__ Vt) {
  __shared__ __align__(16) char ldsb[32768];  // A 16K | B 16K
  int bid = blockIdx.x;
  bid = (bid & 7) * 192 + (bid >> 3);  // XCD swizzle (1536 % 8 == 0, bijective)
  const int bm = bid / 24;             // 0..63 (128-row tile)
  const int bn = bid % 24;             // w = bn/8, head-pair = bn%8
  const int w = bn >> 3;
  const int hp = bn & 7;
  const int wrow = w * 1024 + hp * 128;  // first wt row of this column tile
  const bool isV = (w == 2);
  const int t = threadIdx.x;
  const int wave = t >> 6;
  const int lane = t & 63;
  const int l15 = lane & 15;
  const int wr = wave >> 1;
  const int wc = wave & 1;

  f32x4 acc[4][4];
#pragma unroll
  for (int mi = 0; mi < 4; ++mi)
#pragma unroll
    for (int ni = 0; ni < 4; ++ni) acc[mi][ni] = (f32x4)(0.0f);

  for (int kt = 0; kt < 16; ++kt) {
    const int k0 = kt * 64;
#pragma unroll
    for (int i = 0; i < 4; ++i) {
      const int ci = wave * 4 + i;                 // 0..15
      const int row = ci * 8 + (lane >> 3);        // 0..127
      const int cb = ((lane & 7) * 16) ^ ((row & 7) << 4);
      const size_t ga = ((size_t)(bm * 128 + row) * 1024 + k0) * 2;
      gload16((const char*)xh + ga + cb, ldsb + ci * 1024);
      const size_t gb = ((size_t)(wrow + row) * 1024 + k0) * 2;
      gload16((const char*)wt + gb + cb, ldsb + 16384 + ci * 1024);
    }
    __syncthreads();

#pragma unroll
    for (int ks = 0; ks < 2; ++ks) {
      f16x8 af[4], bfr[4];
#pragma unroll
      for (int mi = 0; mi < 4; ++mi) {
        const int row = wr * 64 + mi * 16 + l15;
        const int cb = (((lane >> 4) * 16) + ks * 64) ^ ((row & 7) << 4);
        af[mi] = *(const f16x8*)(ldsb + row * 128 + cb);
      }
#pragma unroll
      for (int ni = 0; ni < 4; ++ni) {
        const int row = wc * 64 + ni * 16 + l15;
        const int cb = (((lane >> 4) * 16) + ks * 64) ^ ((row & 7) << 4);
        bfr[ni] = *(const f16x8*)(ldsb + 16384 + row * 128 + cb);
      }
#pragma unroll
      for (int mi = 0; mi < 4; ++mi)
#pragma unroll
        for (int ni = 0; ni < 4; ++ni)
          acc[mi][ni] = __builtin_amdgcn_mfma_f32_16x16x32_f16(af[mi], bfr[ni], acc[mi][ni], 0, 0, 0);
    }
    __syncthreads();
  }

  // epilogue: columns 0..127 = head hp*2 + (dl>>6), d = dl & 63
  const int rb = bm * 128 + wr * 64;
#pragma unroll
  for (int mi = 0; mi < 4; ++mi) {
#pragma unroll
    for (int ni = 0; ni < 4; ++ni) {
      f32x4 v = acc[mi][ni];
      const int dl = wc * 64 + ni * 16 + l15;
      const int hh = hp * 2 + (dl >> 6);
      const int d = dl & 63;
      const int m0 = rb + mi * 16 + ((lane >> 4) << 2);
      const int b = m0 >> 11;
      const int ml = m0 & 2047;
      if (isV) {
        uint2 u;
        u.x = packh2(v[0], v[1]);
        u.y = packh2(v[2], v[3]);
        *(uint2*)(Vt + ((size_t)((b * 16 + hh) * 64 + d)) * 2048 + ml) = u;
      } else {
        // Q: fold 1/sqrt(64) AND log2(e) (softmax done in exp2 domain)
        const float sc = (w == 0) ? 0.18033688f : 1.0f;
        f16* A = (w == 0) ? Q : K;
#pragma unroll
        for (int j = 0; j < 4; ++j)
          A[((size_t)(b * 16 + hh) * 2048 + (ml + j)) * 64 + d] = (f16)(v[j] * sc);
      }
    }
  }
}

// ------- kernel 4: flash attention (8-wave blocks, R10 per-wave datapath) -------
// 512 threads, 256 q-rows/block; LDS = 32K KV dbuf + 8x4K P = 64K
// -> 2 blocks/CU, 16 waves/CU, all 512 blocks resident; staging 1 K + 1 V
// gload16 per wave per tile (halved vs 4-wave blocks).
__global__ __launch_bounds__(512, 4) void k_attn(
    const f16* __restrict__ Q, const f16* __restrict__ K,
    const f16* __restrict__ Vt, float* __restrict__ out) {
  __shared__ __align__(16) char ldsb[65536];
  const int raw = blockIdx.x;  // 512 blocks
  // all 8 q-tiles of a head share raw%8 -> same XCD; bijective
  const int bh = (raw & 7) * 8 + (raw >> 6);
  const int qt = (raw >> 3) & 7;
  const int b = bh >> 4;
  const int h = bh & 15;
  const int t = threadIdx.x;
  const int wave = t >> 6;   // 0..7
  const int lane = t & 63;
  const int l15 = lane & 15;
  const int g = lane >> 4;
  char* sP = ldsb + 32768 + wave * 4096;  // per-wave P[32 rows][128 B], XOR-swizzled

  f16x8 qf[2][2];
  const size_t qbase = ((size_t)bh * 2048 + qt * 256 + wave * 32) * 64;
#pragma unroll
  for (int mf = 0; mf < 2; ++mf)
#pragma unroll
    for (int ks = 0; ks < 2; ++ks) {
      const size_t off = qbase + (size_t)(mf * 16 + l15) * 64 + ks * 32 + g * 8;
      qf[mf][ks] = *(const f16x8*)(Q + off);
    }

  f32x4 o[2][4];
  float ms[2], ls[2];
#pragma unroll
  for (int mf = 0; mf < 2; ++mf) { ms[mf] = -1e30f; ls[mf] = 0.0f; }
#pragma unroll
  for (int mf = 0; mf < 2; ++mf)
#pragma unroll
    for (int df = 0; df < 4; ++df) o[mf][df] = (f32x4)(0.0f);

  const size_t kvbase = (size_t)bh * 2048 * 64;

  // per-thread staging addresses: 512 threads cover the full 64x128B tile
  const int srow = wave * 8 + (lane >> 3);                 // 0..63
  const int scb0 = ((lane & 7) * 16) ^ (((lane >> 3) & 7) << 4);

#pragma unroll 1
  for (int kt = 0; kt < 33; ++kt) {
    // stage tile kt into buf kt&1 (issued one iteration ahead of use)
    if (kt < 32) {
      char* dst = ldsb + (kt & 1) * 16384;
      const size_t gk = (kvbase + (size_t)(kt * 64 + srow) * 64) * 2;
      gload16((const char*)K + gk + scb0, dst + wave * 1024);
      const size_t gv = (kvbase + (size_t)srow * 2048 + kt * 64) * 2;
      gload16((const char*)Vt + gv + scb0, dst + 8192 + wave * 1024);
    }
    if (kt == 0) { __syncthreads(); continue; }
    const char* kb = ldsb + ((kt - 1) & 1) * 16384;
    const char* vbuf = kb + 8192;

    // S^T = mfma(K_frag, Q_frag): lane holds, per mf, 16 k-values of q = mf*16+l15
    f32x4 st[2][4];
#pragma unroll
    for (int mf = 0; mf < 2; ++mf)
#pragma unroll
      for (int nf = 0; nf < 4; ++nf) st[mf][nf] = (f32x4)(0.0f);
#pragma unroll
    for (int ks = 0; ks < 2; ++ks) {
      f16x8 kf[4];
#pragma unroll
      for (int nf = 0; nf < 4; ++nf) {
        const int row = nf * 16 + l15;
        const int cb = ((g * 16) + ks * 64) ^ ((row & 7) << 4);
        kf[nf] = *(const f16x8*)(kb + row * 128 + cb);
      }
#pragma unroll
      for (int mf = 0; mf < 2; ++mf)
#pragma unroll
        for (int nf = 0; nf < 4; ++nf)
          st[mf][nf] = __builtin_amdgcn_mfma_f32_16x16x32_f16(kf[nf], qf[mf][ks], st[mf][nf], 0, 0, 0);
    }

    // lane-local online softmax (logits in log2 domain; Q pre-scaled)
#pragma unroll
    for (int mf = 0; mf < 2; ++mf) {
      float rm = fmaxf(fmaxf(fmaxf(st[mf][0][0], st[mf][0][1]), fmaxf(st[mf][0][2], st[mf][0][3])),
                       fmaxf(fmaxf(st[mf][1][0], st[mf][1][1]), fmaxf(st[mf][1][2], st[mf][1][3])));
      rm = fmaxf(rm, fmaxf(fmaxf(fmaxf(st[mf][2][0], st[mf][2][1]), fmaxf(st[mf][2][2], st[mf][2][3])),
                           fmaxf(fmaxf(st[mf][3][0], st[mf][3][1]), fmaxf(st[mf][3][2], st[mf][3][3]))));
      rm = fmaxf(rm, __shfl_xor(rm, 16));
      rm = fmaxf(rm, __shfl_xor(rm, 32));
      if (__any(rm > ms[mf] + 11.5f)) {   // defer-max (THR=8 in base-e)
        const float mnew = fmaxf(ms[mf], rm);
        const float alpha = exp2_fast(ms[mf] - mnew);
        ms[mf] = mnew;
        ls[mf] *= alpha;
        f32x4 av;
#pragma unroll
        for (int j = 0; j < 4; ++j) av[j] = __shfl(alpha, g * 4 + j);
#pragma unroll
        for (int df = 0; df < 4; ++df) o[mf][df] *= av;
      }
      const float m = ms[mf];
      float p[4][4], part = 0.0f;
#pragma unroll
      for (int nf = 0; nf < 4; ++nf) {
#pragma unroll
        for (int j = 0; j < 4; ++j) {
          p[nf][j] = exp2_fast(st[mf][nf][j] - m);
          part += p[nf][j];
        }
      }
      ls[mf] += part;
      const int prow = mf * 16 + l15;
      char* pr = sP + prow * 128;
      const int swz = (prow & 7) << 4;
#pragma unroll
      for (int nf = 0; nf < 4; ++nf) {
        uint2 u;
        u.x = pkrtz(p[nf][0], p[nf][1]);
        u.y = pkrtz(p[nf][2], p[nf][3]);
        *(uint2*)(pr + (((nf << 5) + (g << 3)) ^ swz)) = u;
      }
    }
    asm volatile("" ::: "memory");  // order P ds_writes before pa ds_reads

#pragma unroll
    for (int ks = 0; ks < 2; ++ks) {
      f16x8 pa[2];
#pragma unroll
      for (int mf = 0; mf < 2; ++mf) {
        const int prow = mf * 16 + l15;
        pa[mf] = *(const f16x8*)(sP + prow * 128 + ((ks * 64 + g * 16) ^ ((prow & 7) << 4)));
      }
#pragma unroll
      for (int df = 0; df < 4; ++df) {
        const int row = df * 16 + l15;
        const int cb = ((g * 16) + ks * 64) ^ ((row & 7) << 4);
        const f16x8 vb = *(const f16x8*)(vbuf + row * 128 + cb);
#pragma unroll
        for (int mf = 0; mf < 2; ++mf)
          o[mf][df] = __builtin_amdgcn_mfma_f32_16x16x32_f16(pa[mf], vb, o[mf][df], 0, 0, 0);
      }
    }
    __syncthreads();  // publishes buf staged this iteration; guards P reuse
  }

  // epilogue: O fragment rows are q = mf*16 + g*4 + j; l lives at lane l15 == q
#pragma unroll
  for (int mf = 0; mf < 2; ++mf) {
    float l = ls[mf];
    l += __shfl_xor(l, 16);
    l += __shfl_xor(l, 32);
    const float inv = 1.0f / l;
    f32x4 iv;
#pragma unroll
    for (int j = 0; j < 4; ++j) iv[j] = __shfl(inv, g * 4 + j);
#pragma unroll
    for (int j = 0; j < 4; ++j) {
      const int m = qt * 256 + wave * 32 + mf * 16 + g * 4 + j;
#pragma unroll
      for (int df = 0; df < 4; ++df) {
        const int d = df * 16 + l15;
        out[((size_t)(b * 2048 + m)) * 1024 + h * 64 + d] = o[mf][df][j] * iv[j];
      }
    }
  }
}

// ---------------- launch ----------------
extern "C" void kernel_launch(void* const* d_in, const int* in_sizes, int n_in,
                              void* d_out, int out_size, void* d_ws, size_t ws_size,
                              hipStream_t stream) {
  (void)in_sizes; (void)n_in; (void)out_size; (void)ws_size;
  const float* x  = (const float*)d_in[0];
  const float* Wq = (const float*)d_in[1];
  const float* Wk = (const float*)d_in[2];
  const float* Wv = (const float*)d_in[3];
  float* out = (float*)d_out;

  f16* ws = (f16*)d_ws;  // element (f16) offsets
  f16* xh = ws + 0;            // 8192*1024
  f16* wt = ws + 8388608;      // 3*16*64*1024
  f16* Q  = ws + 11534336;     // 64*2048*64 each
  f16* K  = ws + 19922944;
  f16* Vt = ws + 28311552;     // [bh][64][2048]

  k_half_x<<<4096, 256, 0, stream>>>(x, xh);
  k_prep_w<<<768, 256, 0, stream>>>(Wq, Wk, Wv, wt);
  k_proj<<<1536, 256, 0, stream>>>(xh, wt, Q, K, Vt);
  k_attn<<<512, 512, 0, stream>>>(Q, K, Vt, out);
}